// Round 4
// baseline (111.046 us; speedup 1.0000x reference)
//
#include <hip/hip_runtime.h>
#include <math.h>

#define NG 1024
#define W_RES 128
#define H_RES 128
#define NPIX (W_RES * H_RES)
#define NBLK 8
#define BT (NG / NBLK)          // 128 threads per prep block
#define TILES_X 8
#define NTILE 64                // 8x8 tiles of 16x16 px

// Device-global scratch, sorted by depth rank (rank is a bijection -> every
// slot rewritten each call; no stale-state hazard under re-poison).
__device__ float  s_R2[NG];     // cull radius^2 (w <= 1e-7 outside), <0 => never visible
__device__ float4 s_g0[NG];     // {px, py, -0.5*ia, -ib}
__device__ float4 s_g1[NG];     // {-0.5*ic, log(op), depth, 0}
__device__ float4 s_col[NG];    // {r, g, b, 0}

// ---------------------------------------------------------------------------
// Kernel 1: preprocess + O(N^2) stable rank depth-sort. Grid: 8 x 128.
// ---------------------------------------------------------------------------
__global__ __launch_bounds__(128) void prep_kernel(
    const float* __restrict__ means, const float* __restrict__ log_scales,
    const float* __restrict__ quats, const float* __restrict__ opacity_logits,
    const float* __restrict__ colors, const float* __restrict__ cam,
    const float* __restrict__ look, const float* __restrict__ up) {
  __shared__ __align__(16) float sdepth[NG];
  const int tid = threadIdx.x;
  const int me = blockIdx.x * BT + tid;

  // ---- camera basis (redundant per thread; trivial) ----
  const float cpx = cam[0], cpy = cam[1], cpz = cam[2];
  float fx0 = look[0] - cpx, fy0 = look[1] - cpy, fz0 = look[2] - cpz;
  float inv = 1.f / (sqrtf(fx0 * fx0 + fy0 * fy0 + fz0 * fz0) + 1e-8f);
  const float fX = fx0 * inv, fY = fy0 * inv, fZ = fz0 * inv;
  const float ux0 = up[0], uy0 = up[1], uz0 = up[2];
  float rX0 = fY * uz0 - fZ * uy0, rY0 = fZ * ux0 - fX * uz0, rZ0 = fX * uy0 - fY * ux0;
  inv = 1.f / (sqrtf(rX0 * rX0 + rY0 * rY0 + rZ0 * rZ0) + 1e-8f);
  const float rX = rX0 * inv, rY = rY0 * inv, rZ = rZ0 * inv;
  float uX0 = rY * fZ - rZ * fY, uY0 = rZ * fX - rX * fZ, uZ0 = rX * fY - rY * fX;
  inv = 1.f / (sqrtf(uX0 * uX0 + uY0 * uY0 + uZ0 * uZ0) + 1e-8f);
  const float uX = uX0 * inv, uY = uY0 * inv, uZ = uZ0 * inv;
  const float V00 = rX, V01 = rY, V02 = rZ, V03 = -(rX * cpx + rY * cpy + rZ * cpz);
  const float V10 = uX, V11 = uY, V12 = uZ, V13 = -(uX * cpx + uY * cpy + uZ * cpz);
  const float V20 = -fX, V21 = -fY, V22 = -fZ, V23 = (fX * cpx + fY * cpy + fZ * cpz);

  const float foc = 1.7320508075688772f;  // 1/tan(30deg)
  const float fpx = foc * 64.f;           // focal in pixels (aspect = 1)
  const float fpy = foc * 64.f;

  // ---- all 1024 depths into LDS (8 per thread) ----
#pragma unroll
  for (int i = 0; i < NG / BT; ++i) {
    const int g = i * BT + tid;
    const float mx = means[3 * g + 0], my = means[3 * g + 1], mz = means[3 * g + 2];
    sdepth[g] = -(V20 * mx + V21 * my + V22 * mz + V23);
  }
  __syncthreads();

  // ---- stable rank ----
  const float dme = sdepth[me];
  int rank = 0;
  const float4* dep4 = (const float4*)sdepth;
#pragma unroll 4
  for (int k = 0; k < NG / 4; ++k) {
    const float4 d4 = dep4[k];
    const int j = 4 * k;
    rank += (d4.x < dme || (d4.x == dme && (j + 0) < me)) ? 1 : 0;
    rank += (d4.y < dme || (d4.y == dme && (j + 1) < me)) ? 1 : 0;
    rank += (d4.z < dme || (d4.z == dme && (j + 2) < me)) ? 1 : 0;
    rank += (d4.w < dme || (d4.w == dme && (j + 3) < me)) ? 1 : 0;
  }

  // ---- per-gaussian preprocess ----
  float qw = quats[4 * me + 0], qx = quats[4 * me + 1], qy = quats[4 * me + 2], qz = quats[4 * me + 3];
  float qinv = 1.f / (sqrtf(qw * qw + qx * qx + qy * qy + qz * qz) + 1e-8f);
  qw *= qinv; qx *= qinv; qy *= qinv; qz *= qinv;
  const float R00 = 1.f - 2.f * (qy * qy + qz * qz), R01 = 2.f * (qx * qy - qw * qz), R02 = 2.f * (qx * qz + qw * qy);
  const float R10 = 2.f * (qx * qy + qw * qz), R11 = 1.f - 2.f * (qx * qx + qz * qz), R12 = 2.f * (qy * qz - qw * qx);
  const float R20 = 2.f * (qx * qz - qw * qy), R21 = 2.f * (qy * qz + qw * qx), R22 = 1.f - 2.f * (qx * qx + qy * qy);
  const float s0 = __expf(log_scales[3 * me + 0]);
  const float s1 = __expf(log_scales[3 * me + 1]);
  const float s2 = __expf(log_scales[3 * me + 2]);
  const float M00 = R00 * s0, M01 = R01 * s1, M02 = R02 * s2;
  const float M10 = R10 * s0, M11 = R11 * s1, M12 = R12 * s2;
  const float M20 = R20 * s0, M21 = R21 * s1, M22 = R22 * s2;
  const float c00 = M00 * M00 + M01 * M01 + M02 * M02;
  const float c01 = M00 * M10 + M01 * M11 + M02 * M12;
  const float c02 = M00 * M20 + M01 * M21 + M02 * M22;
  const float c11 = M10 * M10 + M11 * M11 + M12 * M12;
  const float c12 = M10 * M20 + M11 * M21 + M12 * M22;
  const float c22 = M20 * M20 + M21 * M21 + M22 * M22;
  const float mx = means[3 * me + 0], my = means[3 * me + 1], mz = means[3 * me + 2];
  const float tx = V00 * mx + V01 * my + V02 * mz + V03;
  const float ty = V10 * mx + V11 * my + V12 * mz + V13;
  const float tz = V20 * mx + V21 * my + V22 * mz + V23;
  const float depth = -tz;
  const float cw = (fabsf(depth) < 1e-6f) ? 1e-6f : depth;  // clip.w == depth
  const float pxs = (foc * tx / cw + 1.f) * 0.5f * (float)W_RES;
  const float pys = (foc * ty / cw + 1.f) * 0.5f * (float)H_RES;
  const float zs = (fabsf(tz) < 1e-6f) ? 1e-6f : tz;
  const float J00 = fpx / zs, J02 = -fpx * tx / (zs * zs);
  const float J11 = fpy / zs, J12 = -fpy * ty / (zs * zs);
  const float T00 = J00 * V00 + J02 * V20;
  const float T01 = J00 * V01 + J02 * V21;
  const float T02 = J00 * V02 + J02 * V22;
  const float T10 = J11 * V10 + J12 * V20;
  const float T11 = J11 * V11 + J12 * V21;
  const float T12 = J11 * V12 + J12 * V22;
  const float t00 = T00 * c00 + T01 * c01 + T02 * c02;
  const float t01 = T00 * c01 + T01 * c11 + T02 * c12;
  const float t02 = T00 * c02 + T01 * c12 + T02 * c22;
  const float t10 = T10 * c00 + T11 * c01 + T12 * c02;
  const float t11 = T10 * c01 + T11 * c11 + T12 * c12;
  const float t12 = T10 * c02 + T11 * c12 + T12 * c22;
  const float a  = t00 * T00 + t01 * T01 + t02 * T02 + 0.3f;
  const float bb = t00 * T10 + t01 * T11 + t02 * T12;
  const float c  = t10 * T10 + t11 * T11 + t12 * T12 + 0.3f;
  const float det = fmaxf(a * c - bb * bb, 1e-6f);
  const float ia = c / det, ib = -bb / det, ic = a / det;
  const float op = 1.f / (1.f + __expf(-opacity_logits[me]));
  const bool valid = (depth > 0.1f) && (depth < 100.f);
  // cull radius^2: w <= op*exp(-0.5*d2/lam_max) <= 1e-7 outside R2
  const float lam = 0.5f * (a + c) + sqrtf(0.25f * (a - c) * (a - c) + bb * bb);
  float R2v = 2.f * lam * logf(op * 1e7f);
  if (!valid) R2v = -1.f;                 // reference sets w = 0 for invalid
  const float logop = logf(op);
  const float cr = 1.f / (1.f + __expf(-colors[3 * me + 0]));
  const float cg = 1.f / (1.f + __expf(-colors[3 * me + 1]));
  const float cb = 1.f / (1.f + __expf(-colors[3 * me + 2]));

  // ---- scatter into rank position ----
  s_R2[rank]  = R2v;
  s_g0[rank]  = make_float4(pxs, pys, -0.5f * ia, -ib);
  s_g1[rank]  = make_float4(-0.5f * ic, logop, depth, 0.f);
  s_col[rank] = make_float4(cr, cg, cb, 0.f);
}

// ---------------------------------------------------------------------------
// Kernel 2: one 16x16 tile per block (64 blocks x 256 thr). Cull all 1024
// sorted gaussians in 4 stable ballot rounds, stage survivors to LDS, then
// composite front-to-back and write the output directly.
// ---------------------------------------------------------------------------
__global__ __launch_bounds__(256) void render_kernel(float* __restrict__ out) {
  __shared__ float4 tg0[NG];
  __shared__ float4 tg1[NG];
  __shared__ float4 tcol[NG];
  __shared__ int scnt[4];
  const int tid = threadIdx.x;
  const int tile = blockIdx.x;
  const int wid = tid >> 6, lane = tid & 63;
  const int ox = (tile & (TILES_X - 1)) * 16;
  const int oy = (tile >> 3) * 16;
  const float x0 = ox + 0.5f, x1 = ox + 15.5f;
  const float y0 = oy + 0.5f, y1 = oy + 15.5f;

  // ---- stable cull+compact: 4 rounds of 256 ----
  int total = 0;
#pragma unroll
  for (int r = 0; r < 4; ++r) {
    const int g = r * 256 + tid;
    const float4 g0 = s_g0[g];
    const float r2 = s_R2[g];
    const float nx = fminf(fmaxf(g0.x, x0), x1);
    const float ny = fminf(fmaxf(g0.y, y0), y1);
    const float ddx = nx - g0.x, ddy = ny - g0.y;
    const bool surv = (ddx * ddx + ddy * ddy) <= r2;  // NaN-safe: compares false
    const unsigned long long m = __ballot(surv);
    if (lane == 0) scnt[wid] = __popcll(m);
    __syncthreads();
    int base = total;
    for (int w = 0; w < wid; ++w) base += scnt[w];
    total += scnt[0] + scnt[1] + scnt[2] + scnt[3];
    if (surv) {
      const int pos = base + __popcll(m & ((1ull << lane) - 1ull));
      tg0[pos] = g0;
      tg1[pos] = s_g1[g];
      tcol[pos] = s_col[g];
    }
    __syncthreads();  // scnt reused next round; LDS visible for phase 2
  }

  // ---- composite survivors front-to-back (depth order preserved) ----
  const int lx = tid & 15, ly = tid >> 4;
  const float u = (float)(ox + lx) + 0.5f;
  const float v = (float)(oy + ly) + 0.5f;
  float T = 1.f, ar = 0.f, ag = 0.f, ab = 0.f, ad = 0.f, aa = 0.f;
  for (int s = 0; s < total; ++s) {
    const float4 g0 = tg0[s];     // uniform address -> LDS broadcast
    const float4 g1 = tg1[s];
    const float4 cc = tcol[s];
    const float dx = g0.x - u, dy = g0.y - v;
    float pw = dx * (g0.z * dx + g0.w * dy) + g1.x * dy * dy;  // -0.5*quadform
    pw = fminf(pw, 0.f) + g1.y;                                 // + log(op)
    const float w = fminf(__expf(pw), 0.99f);
    const float ctr = T * w;
    ar += ctr * cc.x; ag += ctr * cc.y; ab += ctr * cc.z;
    ad += ctr * g1.z; aa += ctr;
    T *= (1.f - w);
  }
  const int p = (oy + ly) * W_RES + (ox + lx);
  out[0 * NPIX + p] = ar;
  out[1 * NPIX + p] = ag;
  out[2 * NPIX + p] = ab;
  out[3 * NPIX + p] = ad;
  out[4 * NPIX + p] = aa;
}

extern "C" void kernel_launch(void* const* d_in, const int* in_sizes, int n_in,
                              void* d_out, int out_size, void* d_ws, size_t ws_size,
                              hipStream_t stream) {
  const float* means = (const float*)d_in[0];
  const float* log_scales = (const float*)d_in[1];
  const float* quats = (const float*)d_in[2];
  const float* opacity_logits = (const float*)d_in[3];
  const float* colors = (const float*)d_in[4];
  const float* cam = (const float*)d_in[5];
  const float* look = (const float*)d_in[6];
  const float* up = (const float*)d_in[7];
  float* out = (float*)d_out;

  prep_kernel<<<NBLK, BT, 0, stream>>>(means, log_scales, quats, opacity_logits,
                                       colors, cam, look, up);
  render_kernel<<<NTILE, 256, 0, stream>>>(out);
}

// Round 5
// 104.501 us; speedup vs baseline: 1.0626x; 1.0626x over previous
//
#include <hip/hip_runtime.h>
#include <math.h>

#define NG 1024
#define W_RES 128
#define H_RES 128
#define NPIX (W_RES * H_RES)
#define NTILE 64                // 8x8 tiles of 16x16 px
#define TILES_X 8

// ---------------------------------------------------------------------------
// Single fused kernel: 64 blocks x 256 threads, one 16x16 tile per block.
//  A) each block preprocesses all 1024 gaussians (4/thread, redundant across
//     blocks -- trivial), culls vs its tile, ballot-compacts survivors to LDS
//     in stable (ascending global index) order.
//  B) rank-sort survivors by (depth, index) -- O(S^2/256) per thread; equals
//     the reference's stable argsort restricted to survivors.
//  C) per-pixel front-to-back compositing, direct write to out.
// No global scratch, no second launch, no grid-wide dependency.
// ---------------------------------------------------------------------------
__global__ __launch_bounds__(256) void splat_kernel(
    const float* __restrict__ means, const float* __restrict__ log_scales,
    const float* __restrict__ quats, const float* __restrict__ opacity_logits,
    const float* __restrict__ colors, const float* __restrict__ cam,
    const float* __restrict__ look, const float* __restrict__ up,
    float* __restrict__ out) {
  __shared__ float4 tg0[NG];    // {px, py, -0.5*ia, -ib}
  __shared__ float4 tg1[NG];    // {-0.5*ic, log(op), depth, 0}
  __shared__ float4 tcol[NG];   // {r, g, b, 0}
  __shared__ float  skey[NG];   // depth key
  __shared__ int    sidx[NG];   // global index (stable tie-break)
  __shared__ int    sperm[NG];  // sperm[rank] = survivor slot
  __shared__ int    scnt[4];
  const int tid = threadIdx.x;
  const int wid = tid >> 6, lane = tid & 63;
  const int tile = blockIdx.x;
  const int ox = (tile & (TILES_X - 1)) * 16;
  const int oy = (tile >> 3) * 16;
  const float x0 = ox + 0.5f, x1 = ox + 15.5f;
  const float y0 = oy + 0.5f, y1 = oy + 15.5f;

  // ---- camera basis (redundant per thread; trivial) ----
  const float cpx = cam[0], cpy = cam[1], cpz = cam[2];
  float fx0 = look[0] - cpx, fy0 = look[1] - cpy, fz0 = look[2] - cpz;
  float inv = 1.f / (sqrtf(fx0 * fx0 + fy0 * fy0 + fz0 * fz0) + 1e-8f);
  const float fX = fx0 * inv, fY = fy0 * inv, fZ = fz0 * inv;
  const float ux0 = up[0], uy0 = up[1], uz0 = up[2];
  float rX0 = fY * uz0 - fZ * uy0, rY0 = fZ * ux0 - fX * uz0, rZ0 = fX * uy0 - fY * ux0;
  inv = 1.f / (sqrtf(rX0 * rX0 + rY0 * rY0 + rZ0 * rZ0) + 1e-8f);
  const float rX = rX0 * inv, rY = rY0 * inv, rZ = rZ0 * inv;
  float uX0 = rY * fZ - rZ * fY, uY0 = rZ * fX - rX * fZ, uZ0 = rX * fY - rY * fX;
  inv = 1.f / (sqrtf(uX0 * uX0 + uY0 * uY0 + uZ0 * uZ0) + 1e-8f);
  const float uX = uX0 * inv, uY = uY0 * inv, uZ = uZ0 * inv;
  const float V00 = rX, V01 = rY, V02 = rZ, V03 = -(rX * cpx + rY * cpy + rZ * cpz);
  const float V10 = uX, V11 = uY, V12 = uZ, V13 = -(uX * cpx + uY * cpy + uZ * cpz);
  const float V20 = -fX, V21 = -fY, V22 = -fZ, V23 = (fX * cpx + fY * cpy + fZ * cpz);
  const float foc = 1.7320508075688772f;  // 1/tan(30deg)
  const float fpx = foc * 64.f, fpy = foc * 64.f;

  // ---- A: preprocess + cull + stable compaction (4 rounds of 256) ----
  int total = 0;
  for (int r = 0; r < 4; ++r) {
    const int g = r * 256 + tid;
    const float mx = means[3 * g + 0], my = means[3 * g + 1], mz = means[3 * g + 2];
    const float tx = V00 * mx + V01 * my + V02 * mz + V03;
    const float ty = V10 * mx + V11 * my + V12 * mz + V13;
    const float tz = V20 * mx + V21 * my + V22 * mz + V23;
    const float depth = -tz;
    const float cw = (fabsf(depth) < 1e-6f) ? 1e-6f : depth;  // clip.w == depth
    const float pxs = (foc * tx / cw + 1.f) * 0.5f * (float)W_RES;
    const float pys = (foc * ty / cw + 1.f) * 0.5f * (float)H_RES;

    float qw = quats[4 * g + 0], qx = quats[4 * g + 1], qy = quats[4 * g + 2], qz = quats[4 * g + 3];
    const float qinv = 1.f / (sqrtf(qw * qw + qx * qx + qy * qy + qz * qz) + 1e-8f);
    qw *= qinv; qx *= qinv; qy *= qinv; qz *= qinv;
    const float R00 = 1.f - 2.f * (qy * qy + qz * qz), R01 = 2.f * (qx * qy - qw * qz), R02 = 2.f * (qx * qz + qw * qy);
    const float R10 = 2.f * (qx * qy + qw * qz), R11 = 1.f - 2.f * (qx * qx + qz * qz), R12 = 2.f * (qy * qz - qw * qx);
    const float R20 = 2.f * (qx * qz - qw * qy), R21 = 2.f * (qy * qz + qw * qx), R22 = 1.f - 2.f * (qx * qx + qy * qy);
    const float s0 = __expf(log_scales[3 * g + 0]);
    const float s1 = __expf(log_scales[3 * g + 1]);
    const float s2 = __expf(log_scales[3 * g + 2]);
    const float M00 = R00 * s0, M01 = R01 * s1, M02 = R02 * s2;
    const float M10 = R10 * s0, M11 = R11 * s1, M12 = R12 * s2;
    const float M20 = R20 * s0, M21 = R21 * s1, M22 = R22 * s2;
    const float c00 = M00 * M00 + M01 * M01 + M02 * M02;
    const float c01 = M00 * M10 + M01 * M11 + M02 * M12;
    const float c02 = M00 * M20 + M01 * M21 + M02 * M22;
    const float c11 = M10 * M10 + M11 * M11 + M12 * M12;
    const float c12 = M10 * M20 + M11 * M21 + M12 * M22;
    const float c22 = M20 * M20 + M21 * M21 + M22 * M22;
    const float zs = (fabsf(tz) < 1e-6f) ? 1e-6f : tz;
    const float J00 = fpx / zs, J02 = -fpx * tx / (zs * zs);
    const float J11 = fpy / zs, J12 = -fpy * ty / (zs * zs);
    const float T00 = J00 * V00 + J02 * V20;
    const float T01 = J00 * V01 + J02 * V21;
    const float T02 = J00 * V02 + J02 * V22;
    const float T10 = J11 * V10 + J12 * V20;
    const float T11 = J11 * V11 + J12 * V21;
    const float T12 = J11 * V12 + J12 * V22;
    const float t00 = T00 * c00 + T01 * c01 + T02 * c02;
    const float t01 = T00 * c01 + T01 * c11 + T02 * c12;
    const float t02 = T00 * c02 + T01 * c12 + T02 * c22;
    const float t10 = T10 * c00 + T11 * c01 + T12 * c02;
    const float t11 = T10 * c01 + T11 * c11 + T12 * c12;
    const float t12 = T10 * c02 + T11 * c12 + T12 * c22;
    const float a  = t00 * T00 + t01 * T01 + t02 * T02 + 0.3f;
    const float bb = t00 * T10 + t01 * T11 + t02 * T12;
    const float c  = t10 * T10 + t11 * T11 + t12 * T12 + 0.3f;
    const float det = fmaxf(a * c - bb * bb, 1e-6f);
    const float ia = c / det, ib = -bb / det, ic = a / det;
    const float op = 1.f / (1.f + __expf(-opacity_logits[g]));
    const bool valid = (depth > 0.1f) && (depth < 100.f);
    // cull radius^2: w <= op*exp(-0.5*d2/lam_max(cov2d)) <= 1e-7 outside R2
    const float lam = 0.5f * (a + c) + sqrtf(0.25f * (a - c) * (a - c) + bb * bb);
    float R2v = 2.f * lam * logf(op * 1e7f);
    if (!valid) R2v = -1.f;               // reference forces w = 0 when invalid

    const float nx = fminf(fmaxf(pxs, x0), x1);
    const float ny = fminf(fmaxf(pys, y0), y1);
    const float ddx = nx - pxs, ddy = ny - pys;
    const bool surv = (ddx * ddx + ddy * ddy) <= R2v;  // NaN-safe: compares false

    const unsigned long long m = __ballot(surv);
    if (lane == 0) scnt[wid] = __popcll(m);
    __syncthreads();
    int base = total;
    for (int w = 0; w < wid; ++w) base += scnt[w];
    total += scnt[0] + scnt[1] + scnt[2] + scnt[3];
    if (surv) {
      const int pos = base + __popcll(m & ((1ull << lane) - 1ull));
      tg0[pos] = make_float4(pxs, pys, -0.5f * ia, -ib);
      tg1[pos] = make_float4(-0.5f * ic, logf(op), depth, 0.f);
      tcol[pos] = make_float4(1.f / (1.f + __expf(-colors[3 * g + 0])),
                              1.f / (1.f + __expf(-colors[3 * g + 1])),
                              1.f / (1.f + __expf(-colors[3 * g + 2])), 0.f);
      skey[pos] = depth;
      sidx[pos] = g;
    }
    __syncthreads();
  }

  // ---- B: rank-sort survivors by (depth, global index) ----
  for (int s = tid; s < total; s += 256) {
    const float d = skey[s];
    const int id = sidx[s];
    int rank = 0;
    for (int j = 0; j < total; ++j) {
      const float dj = skey[j];
      rank += (dj < d || (dj == d && sidx[j] < id)) ? 1 : 0;
    }
    sperm[rank] = s;
  }
  __syncthreads();

  // ---- C: composite front-to-back ----
  const int lx = tid & 15, ly = tid >> 4;
  const float u = (float)(ox + lx) + 0.5f;
  const float v = (float)(oy + ly) + 0.5f;
  float T = 1.f, ar = 0.f, ag = 0.f, ab = 0.f, ad = 0.f, aa = 0.f;
  for (int t = 0; t < total; ++t) {
    const int s = sperm[t];       // uniform LDS reads -> broadcast
    const float4 g0 = tg0[s];
    const float4 g1 = tg1[s];
    const float4 cc = tcol[s];
    const float dx = g0.x - u, dy = g0.y - v;
    float pw = dx * (g0.z * dx + g0.w * dy) + g1.x * dy * dy;  // -0.5*quadform
    pw = fminf(pw, 0.f) + g1.y;                                 // + log(op)
    const float w = fminf(__expf(pw), 0.99f);
    const float ctr = T * w;
    ar += ctr * cc.x; ag += ctr * cc.y; ab += ctr * cc.z;
    ad += ctr * g1.z; aa += ctr;
    T *= (1.f - w);
  }
  const int p = (oy + ly) * W_RES + (ox + lx);
  out[0 * NPIX + p] = ar;
  out[1 * NPIX + p] = ag;
  out[2 * NPIX + p] = ab;
  out[3 * NPIX + p] = ad;
  out[4 * NPIX + p] = aa;
}

extern "C" void kernel_launch(void* const* d_in, const int* in_sizes, int n_in,
                              void* d_out, int out_size, void* d_ws, size_t ws_size,
                              hipStream_t stream) {
  const float* means = (const float*)d_in[0];
  const float* log_scales = (const float*)d_in[1];
  const float* quats = (const float*)d_in[2];
  const float* opacity_logits = (const float*)d_in[3];
  const float* colors = (const float*)d_in[4];
  const float* cam = (const float*)d_in[5];
  const float* look = (const float*)d_in[6];
  const float* up = (const float*)d_in[7];
  float* out = (float*)d_out;

  splat_kernel<<<NTILE, 256, 0, stream>>>(means, log_scales, quats, opacity_logits,
                                          colors, cam, look, up, out);
}

// Round 6
// 102.808 us; speedup vs baseline: 1.0801x; 1.0165x over previous
//
#include <hip/hip_runtime.h>
#include <math.h>

#define NG 1024
#define W_RES 128
#define H_RES 128
#define NPIX (W_RES * H_RES)
#define NBLK 8
#define BT (NG / NBLK)          // 128 threads per prep block
#define NCHUNK 8
#define CH (NG / NCHUNK)        // 128 gaussians per chunk
#define TILES_X 8
#define NTILE 64                // 8x8 tiles of 16x16 px

// Device-global scratch, sorted by depth rank (rank is a bijection -> every
// slot rewritten each call; g_part fully written by render_kernel).
__device__ float  s_R2[NG];     // cull radius^2 (w <= 1e-7 outside), <0 => never visible
__device__ float4 s_g0[NG];     // {px, py, -0.5*ia, -ib}
__device__ float4 s_g1[NG];     // {-0.5*ic, log(op), depth, 0}
__device__ float4 s_col[NG];    // {r, g, b, 0}
__device__ float  g_part[6 * NCHUNK * NPIX];

// ---------------------------------------------------------------------------
// Kernel 1: preprocess + O(N^2) stable rank depth-sort. Grid: 8 x 128.
// ---------------------------------------------------------------------------
__global__ __launch_bounds__(128) void prep_kernel(
    const float* __restrict__ means, const float* __restrict__ log_scales,
    const float* __restrict__ quats, const float* __restrict__ opacity_logits,
    const float* __restrict__ colors, const float* __restrict__ cam,
    const float* __restrict__ look, const float* __restrict__ up) {
  __shared__ __align__(16) float sdepth[NG];
  const int tid = threadIdx.x;
  const int me = blockIdx.x * BT + tid;

  // ---- camera basis (redundant per thread; trivial) ----
  const float cpx = cam[0], cpy = cam[1], cpz = cam[2];
  float fx0 = look[0] - cpx, fy0 = look[1] - cpy, fz0 = look[2] - cpz;
  float inv = 1.f / (sqrtf(fx0 * fx0 + fy0 * fy0 + fz0 * fz0) + 1e-8f);
  const float fX = fx0 * inv, fY = fy0 * inv, fZ = fz0 * inv;
  const float ux0 = up[0], uy0 = up[1], uz0 = up[2];
  float rX0 = fY * uz0 - fZ * uy0, rY0 = fZ * ux0 - fX * uz0, rZ0 = fX * uy0 - fY * ux0;
  inv = 1.f / (sqrtf(rX0 * rX0 + rY0 * rY0 + rZ0 * rZ0) + 1e-8f);
  const float rX = rX0 * inv, rY = rY0 * inv, rZ = rZ0 * inv;
  float uX0 = rY * fZ - rZ * fY, uY0 = rZ * fX - rX * fZ, uZ0 = rX * fY - rY * fX;
  inv = 1.f / (sqrtf(uX0 * uX0 + uY0 * uY0 + uZ0 * uZ0) + 1e-8f);
  const float uX = uX0 * inv, uY = uY0 * inv, uZ = uZ0 * inv;
  const float V00 = rX, V01 = rY, V02 = rZ, V03 = -(rX * cpx + rY * cpy + rZ * cpz);
  const float V10 = uX, V11 = uY, V12 = uZ, V13 = -(uX * cpx + uY * cpy + uZ * cpz);
  const float V20 = -fX, V21 = -fY, V22 = -fZ, V23 = (fX * cpx + fY * cpy + fZ * cpz);

  const float foc = 1.7320508075688772f;  // 1/tan(30deg)
  const float fpx = foc * 64.f;           // focal in pixels (aspect = 1)
  const float fpy = foc * 64.f;

  // ---- all 1024 depths into LDS (8 per thread) ----
#pragma unroll
  for (int i = 0; i < NG / BT; ++i) {
    const int g = i * BT + tid;
    const float mx = means[3 * g + 0], my = means[3 * g + 1], mz = means[3 * g + 2];
    sdepth[g] = -(V20 * mx + V21 * my + V22 * mz + V23);
  }
  __syncthreads();

  // ---- stable rank ----
  const float dme = sdepth[me];
  int rank = 0;
  const float4* dep4 = (const float4*)sdepth;
#pragma unroll 4
  for (int k = 0; k < NG / 4; ++k) {
    const float4 d4 = dep4[k];
    const int j = 4 * k;
    rank += (d4.x < dme || (d4.x == dme && (j + 0) < me)) ? 1 : 0;
    rank += (d4.y < dme || (d4.y == dme && (j + 1) < me)) ? 1 : 0;
    rank += (d4.z < dme || (d4.z == dme && (j + 2) < me)) ? 1 : 0;
    rank += (d4.w < dme || (d4.w == dme && (j + 3) < me)) ? 1 : 0;
  }

  // ---- per-gaussian preprocess ----
  float qw = quats[4 * me + 0], qx = quats[4 * me + 1], qy = quats[4 * me + 2], qz = quats[4 * me + 3];
  float qinv = 1.f / (sqrtf(qw * qw + qx * qx + qy * qy + qz * qz) + 1e-8f);
  qw *= qinv; qx *= qinv; qy *= qinv; qz *= qinv;
  const float R00 = 1.f - 2.f * (qy * qy + qz * qz), R01 = 2.f * (qx * qy - qw * qz), R02 = 2.f * (qx * qz + qw * qy);
  const float R10 = 2.f * (qx * qy + qw * qz), R11 = 1.f - 2.f * (qx * qx + qz * qz), R12 = 2.f * (qy * qz - qw * qx);
  const float R20 = 2.f * (qx * qz - qw * qy), R21 = 2.f * (qy * qz + qw * qx), R22 = 1.f - 2.f * (qx * qx + qy * qy);
  const float s0 = __expf(log_scales[3 * me + 0]);
  const float s1 = __expf(log_scales[3 * me + 1]);
  const float s2 = __expf(log_scales[3 * me + 2]);
  const float M00 = R00 * s0, M01 = R01 * s1, M02 = R02 * s2;
  const float M10 = R10 * s0, M11 = R11 * s1, M12 = R12 * s2;
  const float M20 = R20 * s0, M21 = R21 * s1, M22 = R22 * s2;
  const float c00 = M00 * M00 + M01 * M01 + M02 * M02;
  const float c01 = M00 * M10 + M01 * M11 + M02 * M12;
  const float c02 = M00 * M20 + M01 * M21 + M02 * M22;
  const float c11 = M10 * M10 + M11 * M11 + M12 * M12;
  const float c12 = M10 * M20 + M11 * M21 + M12 * M22;
  const float c22 = M20 * M20 + M21 * M21 + M22 * M22;
  const float mx = means[3 * me + 0], my = means[3 * me + 1], mz = means[3 * me + 2];
  const float tx = V00 * mx + V01 * my + V02 * mz + V03;
  const float ty = V10 * mx + V11 * my + V12 * mz + V13;
  const float tz = V20 * mx + V21 * my + V22 * mz + V23;
  const float depth = -tz;
  const float cw = (fabsf(depth) < 1e-6f) ? 1e-6f : depth;  // clip.w == depth
  const float pxs = (foc * tx / cw + 1.f) * 0.5f * (float)W_RES;
  const float pys = (foc * ty / cw + 1.f) * 0.5f * (float)H_RES;
  const float zs = (fabsf(tz) < 1e-6f) ? 1e-6f : tz;
  const float J00 = fpx / zs, J02 = -fpx * tx / (zs * zs);
  const float J11 = fpy / zs, J12 = -fpy * ty / (zs * zs);
  const float T00 = J00 * V00 + J02 * V20;
  const float T01 = J00 * V01 + J02 * V21;
  const float T02 = J00 * V02 + J02 * V22;
  const float T10 = J11 * V10 + J12 * V20;
  const float T11 = J11 * V11 + J12 * V21;
  const float T12 = J11 * V12 + J12 * V22;
  const float t00 = T00 * c00 + T01 * c01 + T02 * c02;
  const float t01 = T00 * c01 + T01 * c11 + T02 * c12;
  const float t02 = T00 * c02 + T01 * c12 + T02 * c22;
  const float t10 = T10 * c00 + T11 * c01 + T12 * c02;
  const float t11 = T10 * c01 + T11 * c11 + T12 * c12;
  const float t12 = T10 * c02 + T11 * c12 + T12 * c22;
  const float a  = t00 * T00 + t01 * T01 + t02 * T02 + 0.3f;
  const float bb = t00 * T10 + t01 * T11 + t02 * T12;
  const float c  = t10 * T10 + t11 * T11 + t12 * T12 + 0.3f;
  const float det = fmaxf(a * c - bb * bb, 1e-6f);
  const float ia = c / det, ib = -bb / det, ic = a / det;
  const float op = 1.f / (1.f + __expf(-opacity_logits[me]));
  const bool valid = (depth > 0.1f) && (depth < 100.f);
  // cull radius^2: w <= op*exp(-0.5*d2/lam_max(cov2d)) <= 1e-7 outside R2
  const float lam = 0.5f * (a + c) + sqrtf(0.25f * (a - c) * (a - c) + bb * bb);
  float R2v = 2.f * lam * logf(op * 1e7f);
  if (!valid) R2v = -1.f;                 // reference forces w = 0 when invalid
  const float logop = logf(op);
  const float cr = 1.f / (1.f + __expf(-colors[3 * me + 0]));
  const float cg = 1.f / (1.f + __expf(-colors[3 * me + 1]));
  const float cb = 1.f / (1.f + __expf(-colors[3 * me + 2]));

  // ---- scatter into rank position ----
  s_R2[rank]  = R2v;
  s_g0[rank]  = make_float4(pxs, pys, -0.5f * ia, -ib);
  s_g1[rank]  = make_float4(-0.5f * ic, logop, depth, 0.f);
  s_col[rank] = make_float4(cr, cg, cb, 0.f);
}

// ---------------------------------------------------------------------------
// Kernel 2: chunked tile render. Grid (64 tiles, 8 chunks) x 256 threads =
// 512 blocks (2 blocks/CU). Stage the chunk's 128 param-float4s into LDS
// (coalesced) while culling with an order-preserving ballot compaction; then
// each pixel composites the ~10-40 survivors from LDS broadcast reads.
// ---------------------------------------------------------------------------
__global__ __launch_bounds__(256) void render_kernel() {
  __shared__ float4 lg0[CH], lg1[CH], lcol[CH];
  __shared__ int slist[CH];
  __shared__ int scnt[2];
  const int tid = threadIdx.x;
  const int tile = blockIdx.x;
  const int chunk = blockIdx.y;
  const int base = chunk * CH;
  const int ox = (tile & (TILES_X - 1)) * 16;
  const int oy = (tile >> 3) * 16;
  const float x0 = ox + 0.5f, x1 = ox + 15.5f;
  const float y0 = oy + 0.5f, y1 = oy + 15.5f;

  // ---- stage params to LDS + cull (threads 0-127 cull, 128-255 stage color) ----
  bool surv = false;
  if (tid < CH) {
    const float4 g0v = s_g0[base + tid];
    lg0[tid] = g0v;
    lg1[tid] = s_g1[base + tid];
    const float r2 = s_R2[base + tid];
    const float nx = fminf(fmaxf(g0v.x, x0), x1);
    const float ny = fminf(fmaxf(g0v.y, y0), y1);
    const float ddx = nx - g0v.x, ddy = ny - g0v.y;
    surv = (ddx * ddx + ddy * ddy) <= r2;   // NaN-safe: compares false
  } else {
    lcol[tid - CH] = s_col[base + tid - CH];
  }
  const unsigned long long m = __ballot(surv);   // waves 2,3: m == 0
  const int lane = tid & 63;
  if (tid < CH && lane == 0) scnt[tid >> 6] = __popcll(m);
  __syncthreads();
  const int total = scnt[0] + scnt[1];
  if (surv) {
    const int pos = ((tid >= 64) ? scnt[0] : 0) + __popcll(m & ((1ull << lane) - 1ull));
    slist[pos] = tid;           // index within chunk; ascending -> depth order
  }
  __syncthreads();

  // ---- composite survivors front-to-back ----
  const int lx = tid & 15, ly = tid >> 4;
  const float u = (float)(ox + lx) + 0.5f;
  const float v = (float)(oy + ly) + 0.5f;
  float T = 1.f, ar = 0.f, ag = 0.f, ab = 0.f, ad = 0.f, aa = 0.f;
  for (int s = 0; s < total; ++s) {
    const int j = slist[s];      // uniform -> LDS broadcast
    const float4 g0 = lg0[j];
    const float4 g1 = lg1[j];
    const float4 cc = lcol[j];
    const float dx = g0.x - u, dy = g0.y - v;
    float pw = dx * (g0.z * dx + g0.w * dy) + g1.x * dy * dy;  // -0.5*quadform
    pw = fminf(pw, 0.f) + g1.y;                                 // + log(op)
    const float w = fminf(__expf(pw), 0.99f);
    const float ctr = T * w;
    ar += ctr * cc.x; ag += ctr * cc.y; ab += ctr * cc.z;
    ad += ctr * g1.z; aa += ctr;
    T *= (1.f - w);
  }
  const int p = (oy + ly) * W_RES + (ox + lx);
  const int idx = chunk * NPIX + p;
  g_part[0 * NCHUNK * NPIX + idx] = ar;
  g_part[1 * NCHUNK * NPIX + idx] = ag;
  g_part[2 * NCHUNK * NPIX + idx] = ab;
  g_part[3 * NCHUNK * NPIX + idx] = ad;
  g_part[4 * NCHUNK * NPIX + idx] = aa;
  g_part[5 * NCHUNK * NPIX + idx] = T;
}

// ---------------------------------------------------------------------------
// Kernel 3: fold the NCHUNK partials per pixel: (C,T) o (C',T') = (C+T*C', T*T')
// ---------------------------------------------------------------------------
__global__ __launch_bounds__(256) void combine_kernel(float* __restrict__ out) {
  const int p = blockIdx.x * 256 + threadIdx.x;
  float T = 1.f, r = 0.f, g = 0.f, b = 0.f, d = 0.f, a = 0.f;
#pragma unroll
  for (int ch = 0; ch < NCHUNK; ++ch) {
    const int idx = ch * NPIX + p;
    const float pr = g_part[0 * NCHUNK * NPIX + idx];
    const float pg = g_part[1 * NCHUNK * NPIX + idx];
    const float pb = g_part[2 * NCHUNK * NPIX + idx];
    const float pd = g_part[3 * NCHUNK * NPIX + idx];
    const float pa = g_part[4 * NCHUNK * NPIX + idx];
    const float pT = g_part[5 * NCHUNK * NPIX + idx];
    r += T * pr; g += T * pg; b += T * pb; d += T * pd; a += T * pa;
    T *= pT;
  }
  out[0 * NPIX + p] = r;
  out[1 * NPIX + p] = g;
  out[2 * NPIX + p] = b;
  out[3 * NPIX + p] = d;
  out[4 * NPIX + p] = a;
}

extern "C" void kernel_launch(void* const* d_in, const int* in_sizes, int n_in,
                              void* d_out, int out_size, void* d_ws, size_t ws_size,
                              hipStream_t stream) {
  const float* means = (const float*)d_in[0];
  const float* log_scales = (const float*)d_in[1];
  const float* quats = (const float*)d_in[2];
  const float* opacity_logits = (const float*)d_in[3];
  const float* colors = (const float*)d_in[4];
  const float* cam = (const float*)d_in[5];
  const float* look = (const float*)d_in[6];
  const float* up = (const float*)d_in[7];
  float* out = (float*)d_out;

  prep_kernel<<<NBLK, BT, 0, stream>>>(means, log_scales, quats, opacity_logits,
                                       colors, cam, look, up);
  render_kernel<<<dim3(NTILE, NCHUNK), 256, 0, stream>>>();
  combine_kernel<<<NPIX / 256, 256, 0, stream>>>(out);
}